// Round 1
// baseline (60.146 us; speedup 1.0000x reference)
//
#include <hip/hip_runtime.h>

#define V   1024
#define NH  16384
#define NM  16384

#define BAND_LOW_MAX    500.0f
#define BAND_MID_MAX    2000.0f
#define ENERGY_THRESHOLD 0.5f

// ---------------------------------------------------------------------------
// Pass 1: per-voice raw band energies (no actf factor). One block per voice.
// E_raw[v][b] = sum_{h in band b} harm[v][h]
// ---------------------------------------------------------------------------
__global__ __launch_bounds__(256)
void pass1_band_energy(const float* __restrict__ harm,
                       const float* __restrict__ f0_hz,
                       float* __restrict__ Eraw /* [V][3] */) {
    const int v = blockIdx.x;
    const float f0 = f0_hz[v];
    const float4* h4 = (const float4*)(harm + (size_t)v * NH);

    float e0 = 0.f, e1 = 0.f, e2 = 0.f;
    for (int c = threadIdx.x; c < NH / 4; c += blockDim.x) {
        float4 a = h4[c];
        const int hbase = c * 4;
        #pragma unroll
        for (int j = 0; j < 4; ++j) {
            float amp  = (&a.x)[j];
            float freq = f0 * (float)(hbase + j + 1);   // matches jnp fp32 mul
            if (freq < BAND_LOW_MAX)       e0 += amp;
            else if (freq < BAND_MID_MAX)  e1 += amp;
            else                           e2 += amp;
        }
    }
    // wave(64)-level reduction
    for (int off = 32; off > 0; off >>= 1) {
        e0 += __shfl_down(e0, off);
        e1 += __shfl_down(e1, off);
        e2 += __shfl_down(e2, off);
    }
    __shared__ float s[3][4];   // 256 threads = 4 waves
    const int wid  = threadIdx.x >> 6;
    const int lane = threadIdx.x & 63;
    if (lane == 0) { s[0][wid] = e0; s[1][wid] = e1; s[2][wid] = e2; }
    __syncthreads();
    if (threadIdx.x == 0) {
        float t0 = 0.f, t1 = 0.f, t2 = 0.f;
        #pragma unroll
        for (int i = 0; i < 4; ++i) { t0 += s[0][i]; t1 += s[1][i]; t2 += s[2][i]; }
        Eraw[v * 3 + 0] = t0;
        Eraw[v * 3 + 1] = t1;
        Eraw[v * 3 + 2] = t2;
    }
}

// ---------------------------------------------------------------------------
// Pass 2: global reductions + per-voice gains. Single block, 1024 threads
// (one thread per voice).
// gains[v] = {g_low, g_mid, g_high, noise_scale_effective}
// ---------------------------------------------------------------------------
__global__ __launch_bounds__(1024)
void pass2_gains(const float* __restrict__ Eraw,
                 const float* __restrict__ cw,
                 const float* __restrict__ wd,       /* [V][3] */
                 const int*   __restrict__ is_active,
                 float* __restrict__ gains /* [V][4] */) {
    const int v = threadIdx.x;
    const float e0 = Eraw[v * 3 + 0];
    const float e1 = Eraw[v * 3 + 1];
    const float e2 = Eraw[v * 3 + 2];
    const bool  act  = (is_active[v] != 0);
    const float actf = act ? 1.0f : 0.0f;
    const float w    = cw[v];

    // energy with actf (matches reference: inactive voices contribute 0)
    const float ea0 = e0 * actf, ea1 = e1 * actf, ea2 = e2 * actf;

    // block-wide reductions of 5 quantities
    float r0 = ea0, r1 = ea1, r2 = ea2, r3 = w * actf, r4 = actf;
    for (int off = 32; off > 0; off >>= 1) {
        r0 += __shfl_down(r0, off);
        r1 += __shfl_down(r1, off);
        r2 += __shfl_down(r2, off);
        r3 += __shfl_down(r3, off);
        r4 += __shfl_down(r4, off);
    }
    __shared__ float s[5][16];   // 16 waves
    __shared__ float tot[5];
    const int wid  = threadIdx.x >> 6;
    const int lane = threadIdx.x & 63;
    if (lane == 0) {
        s[0][wid] = r0; s[1][wid] = r1; s[2][wid] = r2;
        s[3][wid] = r3; s[4][wid] = r4;
    }
    __syncthreads();
    if (threadIdx.x < 5) {
        float t = 0.f;
        #pragma unroll
        for (int i = 0; i < 16; ++i) t += s[threadIdx.x][i];
        tot[threadIdx.x] = t;
    }
    __syncthreads();

    const float TE0 = tot[0], TE1 = tot[1], TE2 = tot[2];
    const float TW  = tot[3];
    const bool changed = (tot[4] >= 1.5f);   // n_active >= 2 (exact small-int float)

    const float claim = w / fmaxf(TW, 1e-6f);
    const float share = claim * ENERGY_THRESHOLD;

    const float ea[3] = { ea0, ea1, ea2 };
    const float er[3] = { e0, e1, e2 };
    const float TE[3] = { TE0, TE1, TE2 };

    const float tbefore = e0 + e1 + e2;
    float tafter = 0.f;
    float g[3];
    #pragma unroll
    for (int b = 0; b < 3; ++b) {
        const float excess = ea[b] - share;
        const float exr    = excess / fmaxf(ea[b], 1e-6f);
        const float red    = fmaxf(0.3f, 1.0f - wd[v * 3 + b] * exr * 0.5f);
        const bool apply   = (TE[b] > ENERGY_THRESHOLD) && (ea[b] > 0.0f) &&
                             (excess > 0.0f) && act;
        const float gb = apply ? red : 1.0f;   // gain in reference (pre pass-through)
        tafter += gb * er[b];
        g[b] = changed ? gb : 1.0f;            // gb==1 already for inactive voices
    }

    const float nscale = (tbefore > 1e-6f) ? (tafter / tbefore) : 1.0f;
    const float nse = (changed && act) ? nscale : 1.0f;

    gains[v * 4 + 0] = g[0];
    gains[v * 4 + 1] = g[1];
    gains[v * 4 + 2] = g[2];
    gains[v * 4 + 3] = nse;
}

// ---------------------------------------------------------------------------
// Pass 3: elementwise apply, float4-vectorized.
// out[v][0:NH]      = harm[v]  * g[band(v,h)]
// out[v][NH:NH+NM]  = noise[v] * nscale_eff[v]
// Row = 8192 float4 (4096 harm + 4096 noise); block of 256 never straddles.
// ---------------------------------------------------------------------------
__global__ __launch_bounds__(256)
void pass3_apply(const float* __restrict__ harm,
                 const float* __restrict__ noise,
                 const float* __restrict__ f0_hz,
                 const float* __restrict__ gains,
                 float* __restrict__ out) {
    const int idx = blockIdx.x * 256 + threadIdx.x;  // float4 index
    const int v = idx >> 13;           // 8192 float4 per output row
    const int c = idx & 8191;

    float4 o;
    if (c < 4096) {
        const float4 a = ((const float4*)harm)[(size_t)v * 4096 + c];
        const float f0 = f0_hz[v];
        const float g0 = gains[v * 4 + 0];
        const float g1 = gains[v * 4 + 1];
        const float g2 = gains[v * 4 + 2];
        const int hbase = c * 4;
        #pragma unroll
        for (int j = 0; j < 4; ++j) {
            const float freq = f0 * (float)(hbase + j + 1);
            const float g = (freq < BAND_LOW_MAX) ? g0
                          : (freq < BAND_MID_MAX) ? g1 : g2;
            (&o.x)[j] = (&a.x)[j] * g;
        }
    } else {
        const float4 nm = ((const float4*)noise)[(size_t)v * 4096 + (c - 4096)];
        const float ns = gains[v * 4 + 3];
        o.x = nm.x * ns; o.y = nm.y * ns; o.z = nm.z * ns; o.w = nm.w * ns;
    }
    ((float4*)out)[(size_t)v * 8192 + c] = o;
}

// ---------------------------------------------------------------------------
extern "C" void kernel_launch(void* const* d_in, const int* in_sizes, int n_in,
                              void* d_out, int out_size, void* d_ws, size_t ws_size,
                              hipStream_t stream) {
    const float* harm  = (const float*)d_in[0];
    const float* noise = (const float*)d_in[1];
    const float* f0    = (const float*)d_in[2];
    const float* cw    = (const float*)d_in[3];
    const float* wd    = (const float*)d_in[4];
    const int*   act   = (const int*)d_in[5];
    float* out = (float*)d_out;

    float* Eraw  = (float*)d_ws;               // V*3 floats
    float* gains = Eraw + 4096;                // V*4 floats (offset 16 KiB)

    pass1_band_energy<<<V, 256, 0, stream>>>(harm, f0, Eraw);
    pass2_gains<<<1, 1024, 0, stream>>>(Eraw, cw, wd, act, gains);

    const int n4 = V * 8192;                   // total float4 elements
    pass3_apply<<<n4 / 256, 256, 0, stream>>>(harm, noise, f0, gains, out);
}